// Round 6
// baseline (1381.790 us; speedup 1.0000x reference)
//
#include <hip/hip_runtime.h>
#include <hip/hip_bf16.h>
#include <stdint.h>
#include <math.h>

#define NN 50000
#define DD 128
#define EE 500000
#define ROWT 1563   // ceil(NN/32)

typedef __attribute__((ext_vector_type(8))) short bfx8;   // 8 bf16 = 4 VGPR
typedef __attribute__((ext_vector_type(4))) short bfx4;
typedef __attribute__((ext_vector_type(4))) float f32x4;

static __device__ __forceinline__ short f2bf(float f) {
  union { float f; uint32_t u; } v; v.f = f;
  uint32_t r = (v.u + 0x7fffu + ((v.u >> 16) & 1u)) >> 16;
  return (short)r;
}
static __device__ __forceinline__ float bf2f(short b) {
  union { uint32_t u; float f; } v; v.u = ((uint32_t)(uint16_t)b) << 16;
  return v.f;
}

// A-fragment from global bf16 [rows][128]
static __device__ __forceinline__ bfx8 load_frag_clamp(const short* base, int row0, int k0, int lane) {
  int r = row0 + (lane & 15);
  if (r >= NN) r = NN - 1;
  int k = k0 + ((lane >> 4) << 3);
  return *reinterpret_cast<const bfx8*>(base + (size_t)r * DD + k);
}
// B-fragment from packed weights: [ct][ks][64 lanes][8]
static __device__ __forceinline__ bfx8 load_pk(const short* p, int ct, int ks, int lane) {
  return *reinterpret_cast<const bfx8*>(p + ((((size_t)ct * 4 + ks) * 64 + lane) << 3));
}
// A-fragment from LDS f32 [32][132] -> bf16
static __device__ __forceinline__ bfx8 lds_frag(const float* A, int row0, int ks, int lane) {
  const float* p = A + (size_t)(row0 + (lane & 15)) * 132 + ks * 32 + ((lane >> 4) << 3);
  f32x4 u = *reinterpret_cast<const f32x4*>(p);
  f32x4 v = *reinterpret_cast<const f32x4*>(p + 4);
  bfx8 o;
  o[0]=f2bf(u[0]); o[1]=f2bf(u[1]); o[2]=f2bf(u[2]); o[3]=f2bf(u[3]);
  o[4]=f2bf(v[0]); o[5]=f2bf(v[1]); o[6]=f2bf(v[2]); o[7]=f2bf(v[3]);
  return o;
}

// ---------------- convert fp32 -> bf16 (x_a, x_b) ----------------
struct ConvJobs { const float* src[2]; short* dst[2]; };

__global__ __launch_bounds__(256) void k_convert(ConvJobs jobs) {
  int j = blockIdx.y;
  const float* s = jobs.src[j];
  short* d = jobs.dst[j];
  int i = (blockIdx.x * 256 + threadIdx.x) * 4;
  if (i >= NN * DD) return;
  f32x4 v = *reinterpret_cast<const f32x4*>(s + i);
  bfx4 o;
  o[0]=f2bf(v[0]); o[1]=f2bf(v[1]); o[2]=f2bf(v[2]); o[3]=f2bf(v[3]);
  *reinterpret_cast<bfx4*>(d + i) = o;
}

// ---------------- comb = wih @ Wt, written directly in packed fragment layout ----------------
struct CombJobs { const float* wih[3]; const float* wt[3]; short* out[3]; };

__global__ __launch_bounds__(256) void k_comb(CombJobs cj) {
  int e = blockIdx.y;
  const float* wih = cj.wih[e];
  const float* wt  = cj.wt[e];
  short* out = cj.out[e];
  int tid = blockIdx.x * 256 + threadIdx.x;   // 49152 = 384*128
  int i = tid >> 7, j = tid & 127;            // comb[i][j], i=out row (gate col), j=k
  float acc = 0.f;
  #pragma unroll 4
  for (int k = 0; k < 128; ++k) acc += wih[i * 128 + k] * wt[k * 128 + j];
  int ct = i >> 4;
  int lane = (i & 15) | ((((j & 31) >> 3)) << 4);
  int ks = j >> 5;
  int elem = j & 7;
  out[(((size_t)(ct * 4 + ks) * 64 + lane) << 3) + elem] = f2bf(acc);
}

// ---------------- pack f32 matrix [R][128] into fragment layout bf16 ----------------
struct PackJobs { const float* src[6]; short* dst[6]; int nct[6]; };

__global__ __launch_bounds__(256) void k_pack(PackJobs pj) {
  int j = blockIdx.y;
  int tid = blockIdx.x * 256 + threadIdx.x;
  if (tid >= pj.nct[j] * 256) return;
  int lane = tid & 63, ks = (tid >> 6) & 3, ct = tid >> 8;
  const float* s = pj.src[j] + (size_t)(ct * 16 + (lane & 15)) * 128 + ks * 32 + ((lane >> 4) << 3);
  bfx8 o;
  #pragma unroll
  for (int i = 0; i < 8; ++i) o[i] = f2bf(s[i]);
  *reinterpret_cast<bfx8*>(pj.dst[j] + ((size_t)tid << 3)) = o;
}

// ---------------- CSR build (batched over 3 edge types) ----------------
struct CsrArgs { const int* edge[3]; int* counts[3]; int* offs[3]; uint32_t* bucket[3]; };

__global__ __launch_bounds__(256) void k_hist(CsrArgs a) {
  int t = blockIdx.y;
  int tid = blockIdx.x * 256 + threadIdx.x;
  if (tid >= EE) return;
  atomicAdd(&a.counts[t][a.edge[t][EE + tid]], 1);
}

__global__ __launch_bounds__(1024) void k_scan(CsrArgs a) {
  const int* counts = a.counts[blockIdx.x];
  int* offs = a.offs[blockIdx.x];
  __shared__ int lds[1024];
  const int C = (NN + 1023) / 1024;   // 49
  int t = threadIdx.x;
  int base = t * C;
  int sum = 0;
  for (int i = 0; i < C; ++i) { int idx = base + i; if (idx < NN) sum += counts[idx]; }
  lds[t] = sum;
  __syncthreads();
  for (int off = 1; off < 1024; off <<= 1) {
    int v = (t >= off) ? lds[t - off] : 0;
    __syncthreads();
    lds[t] += v;
    __syncthreads();
  }
  int excl = lds[t] - sum;
  for (int i = 0; i < C; ++i) {
    int idx = base + i;
    if (idx < NN) { offs[idx] = excl; excl += counts[idx]; }
  }
}

// fill: bucket entry packs src (bits 0-19) and local row tgt&31 (bits 20-24)
__global__ __launch_bounds__(256) void k_fill(CsrArgs a) {
  int t = blockIdx.y;
  int tid = blockIdx.x * 256 + threadIdx.x;
  if (tid >= EE) return;
  int tgt = a.edge[t][EE + tid];
  int src = a.edge[t][tid];
  int pos = atomicAdd(&a.offs[t][tgt], 1);
  a.bucket[t][pos] = (uint32_t)src | ((uint32_t)(tgt & 31) << 20);
}

// ---------------- fused: gather -> agg=sum@Ws^T -> GRU -> out ----------------
struct FArgs {
  const int* offs[2]; const uint32_t* bkt[2];
  const short* xsrc[2]; const short* xt[2];
  const short* wsp[2]; const short* combp[2]; const short* whhp[2];
  const float* bih[2]; const float* bhh[2];
  float* out[2]; int mode[2];
};

__global__ __launch_bounds__(256) void k_fused(FArgs a) {
  __shared__ float aggX[32 * 132];
  __shared__ float aggl[32 * 132];
  const int ty = blockIdx.y;
  const int wave = threadIdx.x >> 6, lane = threadIdx.x & 63;
  const int tid = wave * 64 + lane;
  const int rbase = blockIdx.x * 32;
  const int* __restrict__ offs = a.offs[ty];
  const uint32_t* __restrict__ bucket = a.bkt[ty];
  const short* __restrict__ xsrc = a.xsrc[ty];
  const short* __restrict__ xt = a.xt[ty];

  // zero aggX
  #pragma unroll
  for (int i = tid; i < 32 * 132; i += 256) aggX[i] = 0.f;
  __syncthreads();

  // ---- phase 1: branchless edge-parallel gather (group g strides the edge range) ----
  {
    int eStart = rbase ? offs[rbase - 1] : 0;
    int lastRow = rbase + 31; if (lastRow >= NN) lastRow = NN - 1;
    int eEnd = offs[lastRow];
    int g = tid >> 3;                 // 0..31
    int c0 = (tid & 7) * 16;          // column slice of 16
    for (int i = eStart + g; i < eEnd; i += 32) {
      uint32_t e = bucket[i];
      int lr = (int)(e >> 20);
      int s  = (int)(e & 0xFFFFFu);
      const short* p = xsrc + (size_t)s * DD + c0;
      bfx8 u = *reinterpret_cast<const bfx8*>(p);
      bfx8 v = *reinterpret_cast<const bfx8*>(p + 8);
      float* d = aggX + lr * 132 + c0;
      #pragma unroll
      for (int j = 0; j < 8; ++j) atomicAdd(d + j, bf2f(u[j]));
      #pragma unroll
      for (int j = 0; j < 8; ++j) atomicAdd(d + 8 + j, bf2f(v[j]));
    }
  }
  __syncthreads();

  // ---- phase 2: agg = aggX @ Ws^T (wave owns cols wave*32..+32) ----
  {
    const short* wsp = a.wsp[ty];
    f32x4 acc[2][2];
    #pragma unroll
    for (int rf = 0; rf < 2; ++rf)
      #pragma unroll
      for (int c = 0; c < 2; ++c) acc[rf][c] = (f32x4)(0.f);
    #pragma unroll
    for (int ks = 0; ks < 4; ++ks) {
      bfx8 a0 = lds_frag(aggX, 0, ks, lane);
      bfx8 a1 = lds_frag(aggX, 16, ks, lane);
      #pragma unroll
      for (int c = 0; c < 2; ++c) {
        bfx8 b = load_pk(wsp, wave * 2 + c, ks, lane);
        acc[0][c] = __builtin_amdgcn_mfma_f32_16x16x32_bf16(a0, b, acc[0][c], 0, 0, 0);
        acc[1][c] = __builtin_amdgcn_mfma_f32_16x16x32_bf16(a1, b, acc[1][c], 0, 0, 0);
      }
    }
    const int lq = (lane >> 4) << 2;
    #pragma unroll
    for (int rf = 0; rf < 2; ++rf)
      #pragma unroll
      for (int c = 0; c < 2; ++c) {
        int col = wave * 32 + c * 16 + (lane & 15);
        #pragma unroll
        for (int q = 0; q < 4; ++q)
          aggl[(size_t)(rf * 16 + lq + q) * 132 + col] = acc[rf][c][q];
      }
  }
  __syncthreads();

  // ---- phase 3: gi = xt@comb^T, gh = agg@whh^T ----
  const short* combp = a.combp[ty];
  const short* whhp = a.whhp[ty];
  f32x4 ai[2][2][3], ah[2][2][3];
  #pragma unroll
  for (int rf = 0; rf < 2; ++rf)
    #pragma unroll
    for (int c = 0; c < 2; ++c)
      #pragma unroll
      for (int g = 0; g < 3; ++g) { ai[rf][c][g] = (f32x4)(0.f); ah[rf][c][g] = (f32x4)(0.f); }
  #pragma unroll
  for (int ks = 0; ks < 4; ++ks) {
    bfx8 x0 = load_frag_clamp(xt, rbase,      ks * 32, lane);
    bfx8 x1 = load_frag_clamp(xt, rbase + 16, ks * 32, lane);
    bfx8 g0 = lds_frag(aggl, 0, ks, lane);
    bfx8 g1 = lds_frag(aggl, 16, ks, lane);
    #pragma unroll
    for (int g = 0; g < 3; ++g)
      #pragma unroll
      for (int c = 0; c < 2; ++c) {
        int ct = g * 8 + wave * 2 + c;
        bfx8 bi = load_pk(combp, ct, ks, lane);
        bfx8 bh = load_pk(whhp,  ct, ks, lane);
        ai[0][c][g] = __builtin_amdgcn_mfma_f32_16x16x32_bf16(x0, bi, ai[0][c][g], 0, 0, 0);
        ai[1][c][g] = __builtin_amdgcn_mfma_f32_16x16x32_bf16(x1, bi, ai[1][c][g], 0, 0, 0);
        ah[0][c][g] = __builtin_amdgcn_mfma_f32_16x16x32_bf16(g0, bh, ah[0][c][g], 0, 0, 0);
        ah[1][c][g] = __builtin_amdgcn_mfma_f32_16x16x32_bf16(g1, bh, ah[1][c][g], 0, 0, 0);
      }
  }

  // ---- epilogue: gates + store ----
  const float* bih = a.bih[ty];
  const float* bhh = a.bhh[ty];
  float* out = a.out[ty];
  const int mode = a.mode[ty];
  const int lq = (lane >> 4) << 2;
  #pragma unroll
  for (int c = 0; c < 2; ++c) {
    int col = wave * 32 + c * 16 + (lane & 15);
    float bir = bih[col], biz = bih[128 + col], bin = bih[256 + col];
    float bhr = bhh[col], bhz = bhh[128 + col], bhn = bhh[256 + col];
    #pragma unroll
    for (int rf = 0; rf < 2; ++rf)
      #pragma unroll
      for (int q = 0; q < 4; ++q) {
        int lrow = rf * 16 + lq + q;
        int r = rbase + lrow;
        if (r >= NN) continue;
        float ir = ai[rf][c][0][q] + bir, iz = ai[rf][c][1][q] + biz, in = ai[rf][c][2][q] + bin;
        float hr = ah[rf][c][0][q] + bhr, hz = ah[rf][c][1][q] + bhz, hn = ah[rf][c][2][q] + bhn;
        float rr = 1.f / (1.f + expf(-(ir + hr)));
        float zz = 1.f / (1.f + expf(-(iz + hz)));
        float nn = tanhf(in + rr * hn);
        float h  = aggl[(size_t)lrow * 132 + col];
        float res = (1.f - zz) * nn + zz * h;
        size_t o = (size_t)r * DD + col;
        if (mode == 0)      out[o] = fmaxf(res, 0.f);
        else if (mode == 1) out[o] = res;
        else                out[o] = fmaxf((out[o] + res) * 0.5f, 0.f);
      }
  }
}

extern "C" void kernel_launch(void* const* d_in, const int* in_sizes, int n_in,
                              void* d_out, int out_size, void* d_ws, size_t ws_size,
                              hipStream_t stream) {
  const float* x_a = (const float*)d_in[0];
  const float* x_b = (const float*)d_in[1];
  const int* edges[3] = {(const int*)d_in[2], (const int*)d_in[3], (const int*)d_in[4]};
  const float *Ws[3], *Wt[3], *wih[3], *whh[3], *bih[3], *bhh[3];
  for (int e = 0; e < 3; ++e) {
    int b = 5 + e * 6;
    Ws[e]  = (const float*)d_in[b + 0];
    Wt[e]  = (const float*)d_in[b + 1];
    wih[e] = (const float*)d_in[b + 2];
    whh[e] = (const float*)d_in[b + 3];
    bih[e] = (const float*)d_in[b + 4];
    bhh[e] = (const float*)d_in[b + 5];
  }

  // workspace layout (~34 MB)
  char* ws = (char*)d_ws;
  short* xa_bf    = (short*)ws;                      // 12.8 MB
  short* xb_bf    = (short*)(ws + 12800000);         // 12.8 MB
  int*   counts   = (int*)(ws + 25600000);           // 3 x 200 KB
  int*   offs     = (int*)(ws + 26200000);           // 3 x 200 KB
  uint32_t* bucket= (uint32_t*)(ws + 26800000);      // 3 x 2 MB
  short* pk       = (short*)(ws + 32800000);         // 3 x 224 KB
  short *wsp[3], *combp[3], *whhp[3];
  int *countsp[3], *offsp[3]; uint32_t* bktp[3];
  for (int e = 0; e < 3; ++e) {
    short* base = pk + (size_t)e * 114688;
    wsp[e] = base; combp[e] = base + 16384; whhp[e] = base + 65536;
    countsp[e] = counts + (size_t)e * 50000;
    offsp[e]   = offs + (size_t)e * 50000;
    bktp[e]    = bucket + (size_t)e * 500000;
  }

  // 1) convert x_a, x_b to bf16
  ConvJobs cj;
  cj.src[0] = x_a; cj.dst[0] = xa_bf;
  cj.src[1] = x_b; cj.dst[1] = xb_bf;
  hipLaunchKernelGGL(k_convert, dim3(6250, 2), dim3(256), 0, stream, cj);

  // 2) comb = wih @ Wt -> packed bf16 directly
  CombJobs cb;
  for (int e = 0; e < 3; ++e) { cb.wih[e] = wih[e]; cb.wt[e] = Wt[e]; cb.out[e] = combp[e]; }
  hipLaunchKernelGGL(k_comb, dim3(192, 3), dim3(256), 0, stream, cb);

  // 3) pack Ws, whh into fragment layout
  PackJobs pj;
  for (int e = 0; e < 3; ++e) {
    pj.src[e]     = Ws[e];  pj.dst[e]     = wsp[e];  pj.nct[e]     = 8;
    pj.src[3 + e] = whh[e]; pj.dst[3 + e] = whhp[e]; pj.nct[3 + e] = 24;
  }
  hipLaunchKernelGGL(k_pack, dim3(24, 6), dim3(256), 0, stream, pj);

  // 4) CSR build, batched over the 3 edge types
  CsrArgs ca;
  for (int e = 0; e < 3; ++e) {
    ca.edge[e] = edges[e]; ca.counts[e] = countsp[e];
    ca.offs[e] = offsp[e]; ca.bucket[e] = bktp[e];
  }
  (void)hipMemsetAsync(counts, 0, 3 * 50000 * sizeof(int), stream);
  const int EB = (EE + 255) / 256;
  hipLaunchKernelGGL(k_hist, dim3(EB, 3), dim3(256), 0, stream, ca);
  hipLaunchKernelGGL(k_scan, dim3(3), dim3(1024), 0, stream, ca);
  hipLaunchKernelGGL(k_fill, dim3(EB, 3), dim3(256), 0, stream, ca);

  // 5) fused compute: dispatch A = {e1 -> out_b, e2 -> out_a raw}; dispatch B = {e3 -> out_a rmw}
  float* out_a = (float*)d_out;
  float* out_b = (float*)d_out + (size_t)NN * DD;

  FArgs fa;
  fa.offs[0] = offsp[0]; fa.bkt[0] = bktp[0];
  fa.xsrc[0] = xa_bf; fa.xt[0] = xb_bf;
  fa.wsp[0] = wsp[0]; fa.combp[0] = combp[0]; fa.whhp[0] = whhp[0];
  fa.bih[0] = bih[0]; fa.bhh[0] = bhh[0];
  fa.out[0] = out_b; fa.mode[0] = 0;
  fa.offs[1] = offsp[1]; fa.bkt[1] = bktp[1];
  fa.xsrc[1] = xb_bf; fa.xt[1] = xa_bf;
  fa.wsp[1] = wsp[1]; fa.combp[1] = combp[1]; fa.whhp[1] = whhp[1];
  fa.bih[1] = bih[1]; fa.bhh[1] = bhh[1];
  fa.out[1] = out_a; fa.mode[1] = 1;
  hipLaunchKernelGGL(k_fused, dim3(ROWT, 2), dim3(256), 0, stream, fa);

  FArgs fb;
  fb.offs[0] = offsp[2]; fb.bkt[0] = bktp[2];
  fb.xsrc[0] = xb_bf; fb.xt[0] = xa_bf;
  fb.wsp[0] = wsp[2]; fb.combp[0] = combp[2]; fb.whhp[0] = whhp[2];
  fb.bih[0] = bih[2]; fb.bhh[0] = bhh[2];
  fb.out[0] = out_a; fb.mode[0] = 2;
  fb.offs[1] = fb.offs[0]; fb.bkt[1] = fb.bkt[0];
  fb.xsrc[1] = fb.xsrc[0]; fb.xt[1] = fb.xt[0];
  fb.wsp[1] = fb.wsp[0]; fb.combp[1] = fb.combp[0]; fb.whhp[1] = fb.whhp[0];
  fb.bih[1] = fb.bih[0]; fb.bhh[1] = fb.bhh[0];
  fb.out[1] = fb.out[0]; fb.mode[1] = fb.mode[0];
  hipLaunchKernelGGL(k_fused, dim3(ROWT, 1), dim3(256), 0, stream, fb);
}

// Round 7
// 524.380 us; speedup vs baseline: 2.6351x; 2.6351x over previous
//
#include <hip/hip_runtime.h>
#include <hip/hip_bf16.h>
#include <stdint.h>
#include <math.h>

#define NN 50000
#define DD 128
#define EE 500000
#define ROWT 1563   // ceil(NN/32)

typedef __attribute__((ext_vector_type(8))) short bfx8;   // 8 bf16 = 4 VGPR
typedef __attribute__((ext_vector_type(4))) short bfx4;
typedef __attribute__((ext_vector_type(4))) float f32x4;

static __device__ __forceinline__ short f2bf(float f) {
  union { float f; uint32_t u; } v; v.f = f;
  uint32_t r = (v.u + 0x7fffu + ((v.u >> 16) & 1u)) >> 16;
  return (short)r;
}
static __device__ __forceinline__ float bf2f(short b) {
  union { uint32_t u; float f; } v; v.u = ((uint32_t)(uint16_t)b) << 16;
  return v.f;
}

// A-fragment from global bf16 [rows][128]
static __device__ __forceinline__ bfx8 load_frag_clamp(const short* base, int row0, int k0, int lane) {
  int r = row0 + (lane & 15);
  if (r >= NN) r = NN - 1;
  int k = k0 + ((lane >> 4) << 3);
  return *reinterpret_cast<const bfx8*>(base + (size_t)r * DD + k);
}
// B-fragment from packed weights: [ct][ks][64 lanes][8]
static __device__ __forceinline__ bfx8 load_pk(const short* p, int ct, int ks, int lane) {
  return *reinterpret_cast<const bfx8*>(p + ((((size_t)ct * 4 + ks) * 64 + lane) << 3));
}
// A-fragment from LDS bf16 [32][136]
static __device__ __forceinline__ bfx8 lds_fragb(const short* A, int row0, int ks, int lane) {
  return *reinterpret_cast<const bfx8*>(A + (size_t)(row0 + (lane & 15)) * 136 + ks * 32 + ((lane >> 4) << 3));
}

// ---------------- convert fp32 -> bf16 (x_a, x_b) ----------------
struct ConvJobs { const float* src[2]; short* dst[2]; };

__global__ __launch_bounds__(256) void k_convert(ConvJobs jobs) {
  int j = blockIdx.y;
  const float* s = jobs.src[j];
  short* d = jobs.dst[j];
  int i = (blockIdx.x * 256 + threadIdx.x) * 4;
  if (i >= NN * DD) return;
  f32x4 v = *reinterpret_cast<const f32x4*>(s + i);
  bfx4 o;
  o[0]=f2bf(v[0]); o[1]=f2bf(v[1]); o[2]=f2bf(v[2]); o[3]=f2bf(v[3]);
  *reinterpret_cast<bfx4*>(d + i) = o;
}

// ---------------- comb = wih @ Wt, written directly in packed fragment layout ----------------
struct CombJobs { const float* wih[3]; const float* wt[3]; short* out[3]; };

__global__ __launch_bounds__(256) void k_comb(CombJobs cj) {
  int e = blockIdx.y;
  const float* wih = cj.wih[e];
  const float* wt  = cj.wt[e];
  short* out = cj.out[e];
  int tid = blockIdx.x * 256 + threadIdx.x;   // 49152 = 384*128
  int i = tid >> 7, j = tid & 127;            // comb[i][j]
  float acc = 0.f;
  #pragma unroll 4
  for (int k = 0; k < 128; ++k) acc += wih[i * 128 + k] * wt[k * 128 + j];
  int ct = i >> 4;
  int lane = (i & 15) | ((((j & 31) >> 3)) << 4);
  int ks = j >> 5;
  int elem = j & 7;
  out[(((size_t)(ct * 4 + ks) * 64 + lane) << 3) + elem] = f2bf(acc);
}

// ---------------- pack f32 matrix [R][128] into fragment layout bf16 ----------------
struct PackJobs { const float* src[6]; short* dst[6]; int nct[6]; };

__global__ __launch_bounds__(256) void k_pack(PackJobs pj) {
  int j = blockIdx.y;
  int tid = blockIdx.x * 256 + threadIdx.x;
  if (tid >= pj.nct[j] * 256) return;
  int lane = tid & 63, ks = (tid >> 6) & 3, ct = tid >> 8;
  const float* s = pj.src[j] + (size_t)(ct * 16 + (lane & 15)) * 128 + ks * 32 + ((lane >> 4) << 3);
  bfx8 o;
  #pragma unroll
  for (int i = 0; i < 8; ++i) o[i] = f2bf(s[i]);
  *reinterpret_cast<bfx8*>(pj.dst[j] + ((size_t)tid << 3)) = o;
}

// ---------------- CSR build (batched over 3 edge types) ----------------
struct CsrArgs { const int* edge[3]; int* counts[3]; int* offs[3]; int* bucket[3]; };

__global__ __launch_bounds__(256) void k_hist(CsrArgs a) {
  int t = blockIdx.y;
  int tid = blockIdx.x * 256 + threadIdx.x;
  if (tid >= EE) return;
  atomicAdd(&a.counts[t][a.edge[t][EE + tid]], 1);
}

__global__ __launch_bounds__(1024) void k_scan(CsrArgs a) {
  const int* counts = a.counts[blockIdx.x];
  int* offs = a.offs[blockIdx.x];
  __shared__ int lds[1024];
  const int C = (NN + 1023) / 1024;   // 49
  int t = threadIdx.x;
  int base = t * C;
  int sum = 0;
  for (int i = 0; i < C; ++i) { int idx = base + i; if (idx < NN) sum += counts[idx]; }
  lds[t] = sum;
  __syncthreads();
  for (int off = 1; off < 1024; off <<= 1) {
    int v = (t >= off) ? lds[t - off] : 0;
    __syncthreads();
    lds[t] += v;
    __syncthreads();
  }
  int excl = lds[t] - sum;
  for (int i = 0; i < C; ++i) {
    int idx = base + i;
    if (idx < NN) { offs[idx] = excl; excl += counts[idx]; }
  }
}

__global__ __launch_bounds__(256) void k_fill(CsrArgs a) {
  int t = blockIdx.y;
  int tid = blockIdx.x * 256 + threadIdx.x;
  if (tid >= EE) return;
  int tgt = a.edge[t][EE + tid];
  int src = a.edge[t][tid];
  int pos = atomicAdd(&a.offs[t][tgt], 1);
  a.bucket[t][pos] = src;
}

// ---------------- fused: gather -> agg=sum@Ws^T -> GRU -> out ----------------
struct FArgs {
  const int* offs[2]; const int* bkt[2];
  const short* xsrc[2]; const short* xt[2];
  const short* wsp[2]; const short* combp[2]; const short* whhp[2];
  const float* bih[2]; const float* bhh[2];
  float* out[2]; int mode[2];
};

__global__ __launch_bounds__(256) void k_fused(FArgs a) {
  __shared__ short aggXb[32 * 136];   // bf16 gathered sums (MFMA A source)
  __shared__ float aggl [32 * 132];   // f32 agg (GRU h)
  __shared__ short agglb[32 * 136];   // bf16 agg (MFMA A source)
  const int ty = blockIdx.y;
  const int wave = threadIdx.x >> 6, lane = threadIdx.x & 63;
  const int tid = wave * 64 + lane;
  const int rbase = blockIdx.x * 32;
  const int* __restrict__ offs = a.offs[ty];
  const int* __restrict__ bucket = a.bkt[ty];
  const short* __restrict__ xsrc = a.xsrc[ty];
  const short* __restrict__ xt = a.xt[ty];

  // ---- phase 1: row-serial register gather, unrolled x4 ----
  {
    int lrow = wave * 8 + (lane >> 3);        // 0..31
    int row = rbase + lrow;
    if (row >= NN) row = NN - 1;              // dup of last row; outputs guarded
    int c0 = (lane & 7) * 16;                 // 16-col slice
    int start = row ? offs[row - 1] : 0;
    int end = offs[row];
    f32x4 s0 = (f32x4)(0.f), s1 = (f32x4)(0.f), s2 = (f32x4)(0.f), s3 = (f32x4)(0.f);
    int i = start;
    for (; i + 4 <= end; i += 4) {
      int e0 = bucket[i], e1 = bucket[i + 1], e2 = bucket[i + 2], e3 = bucket[i + 3];
      const short* p0 = xsrc + (size_t)e0 * DD + c0;
      const short* p1 = xsrc + (size_t)e1 * DD + c0;
      const short* p2 = xsrc + (size_t)e2 * DD + c0;
      const short* p3 = xsrc + (size_t)e3 * DD + c0;
      bfx8 u0 = *reinterpret_cast<const bfx8*>(p0), v0 = *reinterpret_cast<const bfx8*>(p0 + 8);
      bfx8 u1 = *reinterpret_cast<const bfx8*>(p1), v1 = *reinterpret_cast<const bfx8*>(p1 + 8);
      bfx8 u2 = *reinterpret_cast<const bfx8*>(p2), v2 = *reinterpret_cast<const bfx8*>(p2 + 8);
      bfx8 u3 = *reinterpret_cast<const bfx8*>(p3), v3 = *reinterpret_cast<const bfx8*>(p3 + 8);
      #pragma unroll
      for (int j = 0; j < 4; ++j) {
        s0[j] += bf2f(u0[j]) + bf2f(u1[j]) + bf2f(u2[j]) + bf2f(u3[j]);
        s1[j] += bf2f(u0[4+j]) + bf2f(u1[4+j]) + bf2f(u2[4+j]) + bf2f(u3[4+j]);
        s2[j] += bf2f(v0[j]) + bf2f(v1[j]) + bf2f(v2[j]) + bf2f(v3[j]);
        s3[j] += bf2f(v0[4+j]) + bf2f(v1[4+j]) + bf2f(v2[4+j]) + bf2f(v3[4+j]);
      }
    }
    for (; i < end; ++i) {
      const short* p = xsrc + (size_t)bucket[i] * DD + c0;
      bfx8 u = *reinterpret_cast<const bfx8*>(p), v = *reinterpret_cast<const bfx8*>(p + 8);
      #pragma unroll
      for (int j = 0; j < 4; ++j) {
        s0[j] += bf2f(u[j]); s1[j] += bf2f(u[4+j]);
        s2[j] += bf2f(v[j]); s3[j] += bf2f(v[4+j]);
      }
    }
    short* d = aggXb + (size_t)lrow * 136 + c0;
    bfx8 o0, o1;
    #pragma unroll
    for (int j = 0; j < 4; ++j) {
      o0[j] = f2bf(s0[j]); o0[4+j] = f2bf(s1[j]);
      o1[j] = f2bf(s2[j]); o1[4+j] = f2bf(s3[j]);
    }
    *reinterpret_cast<bfx8*>(d) = o0;
    *reinterpret_cast<bfx8*>(d + 8) = o1;
  }
  __syncthreads();

  // ---- phase 2: agg = aggX @ Ws^T (wave owns cols wave*32..+32) ----
  {
    const short* wsp = a.wsp[ty];
    f32x4 acc[2][2];
    #pragma unroll
    for (int rf = 0; rf < 2; ++rf)
      #pragma unroll
      for (int c = 0; c < 2; ++c) acc[rf][c] = (f32x4)(0.f);
    #pragma unroll
    for (int ks = 0; ks < 4; ++ks) {
      bfx8 a0 = lds_fragb(aggXb, 0, ks, lane);
      bfx8 a1 = lds_fragb(aggXb, 16, ks, lane);
      #pragma unroll
      for (int c = 0; c < 2; ++c) {
        bfx8 b = load_pk(wsp, wave * 2 + c, ks, lane);
        acc[0][c] = __builtin_amdgcn_mfma_f32_16x16x32_bf16(a0, b, acc[0][c], 0, 0, 0);
        acc[1][c] = __builtin_amdgcn_mfma_f32_16x16x32_bf16(a1, b, acc[1][c], 0, 0, 0);
      }
    }
    const int lq = (lane >> 4) << 2;
    #pragma unroll
    for (int rf = 0; rf < 2; ++rf)
      #pragma unroll
      for (int c = 0; c < 2; ++c) {
        int col = wave * 32 + c * 16 + (lane & 15);
        #pragma unroll
        for (int q = 0; q < 4; ++q) {
          int lrow = rf * 16 + lq + q;
          aggl [(size_t)lrow * 132 + col] = acc[rf][c][q];
          agglb[(size_t)lrow * 136 + col] = f2bf(acc[rf][c][q]);
        }
      }
  }
  __syncthreads();

  // ---- phase 3: gi = xt@comb^T, gh = agg@whh^T ----
  const short* combp = a.combp[ty];
  const short* whhp = a.whhp[ty];
  f32x4 ai[2][2][3], ah[2][2][3];
  #pragma unroll
  for (int rf = 0; rf < 2; ++rf)
    #pragma unroll
    for (int c = 0; c < 2; ++c)
      #pragma unroll
      for (int g = 0; g < 3; ++g) { ai[rf][c][g] = (f32x4)(0.f); ah[rf][c][g] = (f32x4)(0.f); }
  #pragma unroll
  for (int ks = 0; ks < 4; ++ks) {
    bfx8 x0 = load_frag_clamp(xt, rbase,      ks * 32, lane);
    bfx8 x1 = load_frag_clamp(xt, rbase + 16, ks * 32, lane);
    bfx8 g0 = lds_fragb(agglb, 0, ks, lane);
    bfx8 g1 = lds_fragb(agglb, 16, ks, lane);
    #pragma unroll
    for (int g = 0; g < 3; ++g)
      #pragma unroll
      for (int c = 0; c < 2; ++c) {
        int ct = g * 8 + wave * 2 + c;
        bfx8 bi = load_pk(combp, ct, ks, lane);
        bfx8 bh = load_pk(whhp,  ct, ks, lane);
        ai[0][c][g] = __builtin_amdgcn_mfma_f32_16x16x32_bf16(x0, bi, ai[0][c][g], 0, 0, 0);
        ai[1][c][g] = __builtin_amdgcn_mfma_f32_16x16x32_bf16(x1, bi, ai[1][c][g], 0, 0, 0);
        ah[0][c][g] = __builtin_amdgcn_mfma_f32_16x16x32_bf16(g0, bh, ah[0][c][g], 0, 0, 0);
        ah[1][c][g] = __builtin_amdgcn_mfma_f32_16x16x32_bf16(g1, bh, ah[1][c][g], 0, 0, 0);
      }
  }

  // ---- epilogue: gates + store ----
  const float* bih = a.bih[ty];
  const float* bhh = a.bhh[ty];
  float* out = a.out[ty];
  const int mode = a.mode[ty];
  const int lq = (lane >> 4) << 2;
  #pragma unroll
  for (int c = 0; c < 2; ++c) {
    int col = wave * 32 + c * 16 + (lane & 15);
    float bir = bih[col], biz = bih[128 + col], bin = bih[256 + col];
    float bhr = bhh[col], bhz = bhh[128 + col], bhn = bhh[256 + col];
    #pragma unroll
    for (int rf = 0; rf < 2; ++rf)
      #pragma unroll
      for (int q = 0; q < 4; ++q) {
        int lrow = rf * 16 + lq + q;
        int r = rbase + lrow;
        if (r >= NN) continue;
        float ir = ai[rf][c][0][q] + bir, iz = ai[rf][c][1][q] + biz, in = ai[rf][c][2][q] + bin;
        float hr = ah[rf][c][0][q] + bhr, hz = ah[rf][c][1][q] + bhz, hn = ah[rf][c][2][q] + bhn;
        float rr = 1.f / (1.f + expf(-(ir + hr)));
        float zz = 1.f / (1.f + expf(-(iz + hz)));
        float nn = tanhf(in + rr * hn);
        float h  = aggl[(size_t)lrow * 132 + col];
        float res = (1.f - zz) * nn + zz * h;
        size_t o = (size_t)r * DD + col;
        if (mode == 0)      out[o] = fmaxf(res, 0.f);
        else if (mode == 1) out[o] = res;
        else                out[o] = fmaxf((out[o] + res) * 0.5f, 0.f);
      }
  }
}

extern "C" void kernel_launch(void* const* d_in, const int* in_sizes, int n_in,
                              void* d_out, int out_size, void* d_ws, size_t ws_size,
                              hipStream_t stream) {
  const float* x_a = (const float*)d_in[0];
  const float* x_b = (const float*)d_in[1];
  const int* edges[3] = {(const int*)d_in[2], (const int*)d_in[3], (const int*)d_in[4]};
  const float *Ws[3], *Wt[3], *wih[3], *whh[3], *bih[3], *bhh[3];
  for (int e = 0; e < 3; ++e) {
    int b = 5 + e * 6;
    Ws[e]  = (const float*)d_in[b + 0];
    Wt[e]  = (const float*)d_in[b + 1];
    wih[e] = (const float*)d_in[b + 2];
    whh[e] = (const float*)d_in[b + 3];
    bih[e] = (const float*)d_in[b + 4];
    bhh[e] = (const float*)d_in[b + 5];
  }

  // workspace layout (~34 MB)
  char* ws = (char*)d_ws;
  short* xa_bf    = (short*)ws;                      // 12.8 MB
  short* xb_bf    = (short*)(ws + 12800000);         // 12.8 MB
  int*   counts   = (int*)(ws + 25600000);           // 3 x 200 KB
  int*   offs     = (int*)(ws + 26200000);           // 3 x 200 KB
  int*   bucket   = (int*)(ws + 26800000);           // 3 x 2 MB
  short* pk       = (short*)(ws + 32800000);         // 3 x 224 KB
  short *wsp[3], *combp[3], *whhp[3];
  int *countsp[3], *offsp[3]; int* bktp[3];
  for (int e = 0; e < 3; ++e) {
    short* base = pk + (size_t)e * 114688;
    wsp[e] = base; combp[e] = base + 16384; whhp[e] = base + 65536;
    countsp[e] = counts + (size_t)e * 50000;
    offsp[e]   = offs + (size_t)e * 50000;
    bktp[e]    = bucket + (size_t)e * 500000;
  }

  // 1) convert x_a, x_b to bf16
  ConvJobs cj;
  cj.src[0] = x_a; cj.dst[0] = xa_bf;
  cj.src[1] = x_b; cj.dst[1] = xb_bf;
  hipLaunchKernelGGL(k_convert, dim3(6250, 2), dim3(256), 0, stream, cj);

  // 2) comb = wih @ Wt -> packed bf16 directly
  CombJobs cb;
  for (int e = 0; e < 3; ++e) { cb.wih[e] = wih[e]; cb.wt[e] = Wt[e]; cb.out[e] = combp[e]; }
  hipLaunchKernelGGL(k_comb, dim3(192, 3), dim3(256), 0, stream, cb);

  // 3) pack Ws, whh into fragment layout
  PackJobs pj;
  for (int e = 0; e < 3; ++e) {
    pj.src[e]     = Ws[e];  pj.dst[e]     = wsp[e];  pj.nct[e]     = 8;
    pj.src[3 + e] = whh[e]; pj.dst[3 + e] = whhp[e]; pj.nct[3 + e] = 24;
  }
  hipLaunchKernelGGL(k_pack, dim3(24, 6), dim3(256), 0, stream, pj);

  // 4) CSR build, batched over the 3 edge types
  CsrArgs ca;
  for (int e = 0; e < 3; ++e) {
    ca.edge[e] = edges[e]; ca.counts[e] = countsp[e];
    ca.offs[e] = offsp[e]; ca.bucket[e] = bktp[e];
  }
  (void)hipMemsetAsync(counts, 0, 3 * 50000 * sizeof(int), stream);
  const int EB = (EE + 255) / 256;
  hipLaunchKernelGGL(k_hist, dim3(EB, 3), dim3(256), 0, stream, ca);
  hipLaunchKernelGGL(k_scan, dim3(3), dim3(1024), 0, stream, ca);
  hipLaunchKernelGGL(k_fill, dim3(EB, 3), dim3(256), 0, stream, ca);

  // 5) fused compute: dispatch A = {e1 -> out_b, e2 -> out_a raw}; dispatch B = {e3 -> out_a rmw}
  float* out_a = (float*)d_out;
  float* out_b = (float*)d_out + (size_t)NN * DD;

  FArgs fa;
  fa.offs[0] = offsp[0]; fa.bkt[0] = bktp[0];
  fa.xsrc[0] = xa_bf; fa.xt[0] = xb_bf;
  fa.wsp[0] = wsp[0]; fa.combp[0] = combp[0]; fa.whhp[0] = whhp[0];
  fa.bih[0] = bih[0]; fa.bhh[0] = bhh[0];
  fa.out[0] = out_b; fa.mode[0] = 0;
  fa.offs[1] = offsp[1]; fa.bkt[1] = bktp[1];
  fa.xsrc[1] = xb_bf; fa.xt[1] = xa_bf;
  fa.wsp[1] = wsp[1]; fa.combp[1] = combp[1]; fa.whhp[1] = whhp[1];
  fa.bih[1] = bih[1]; fa.bhh[1] = bhh[1];
  fa.out[1] = out_a; fa.mode[1] = 1;
  hipLaunchKernelGGL(k_fused, dim3(ROWT, 2), dim3(256), 0, stream, fa);

  FArgs fb;
  fb.offs[0] = offsp[2]; fb.bkt[0] = bktp[2];
  fb.xsrc[0] = xb_bf; fb.xt[0] = xa_bf;
  fb.wsp[0] = wsp[2]; fb.combp[0] = combp[2]; fb.whhp[0] = whhp[2];
  fb.bih[0] = bih[2]; fb.bhh[0] = bhh[2];
  fb.out[0] = out_a; fb.mode[0] = 2;
  fb.offs[1] = fb.offs[0]; fb.bkt[1] = fb.bkt[0];
  fb.xsrc[1] = fb.xsrc[0]; fb.xt[1] = fb.xt[0];
  fb.wsp[1] = fb.wsp[0]; fb.combp[1] = fb.combp[0]; fb.whhp[1] = fb.whhp[0];
  fb.bih[1] = fb.bih[0]; fb.bhh[1] = fb.bhh[0];
  fb.out[1] = fb.out[0]; fb.mode[1] = fb.mode[0];
  hipLaunchKernelGGL(k_fused, dim3(ROWT, 1), dim3(256), 0, stream, fb);
}